// Round 5
// baseline (1600.904 us; speedup 1.0000x reference)
//
#include <hip/hip_runtime.h>
#include <hip/hip_bf16.h>

#define Bn 64
#define Kn 24
#define Nn 934
#define NBLK 4
#define GCH 234          // points per gram block
#define RNDS 15          // 15 * 16 = 240 >= 234
#define GPK 12090        // 155*156/2 packed lower (row 154 = rhs row)

#define G_BYTES ((size_t)Bn * GPK * 8)

// ---------------- k_pre: stream-reduce b_s_ and xm over K -------------------
__global__ __launch_bounds__(1024) void k_pre(
    const float* __restrict__ uv, const float* __restrict__ xm,
    const float* __restrict__ bs, const float* __restrict__ Wp,
    const float* __restrict__ m00, const float* __restrict__ m11,
    const float* __restrict__ m02, const float* __restrict__ m12,
    float* __restrict__ pre)
{
    __shared__ float smL[32][30];
    __shared__ float xsL[32][3];
    const int tid = threadIdx.x;
    const int b = blockIdx.y;
    const int n0 = blockIdx.x * 32;
    const float f0 = m00[b], f1 = m11[b], cx = m02[b], cy = m12[b];

    if (tid < 960) {
        const int ni = tid / 30, c = tid - ni * 30;
        const int nc = min(n0 + ni, Nn - 1);
        float acc = 0.0f;
        const float* bp = bs + ((size_t)(b * Kn) * Nn + nc) * 30 + c;
        #pragma unroll
        for (int k = 0; k < Kn; ++k) acc += bp[(size_t)k * Nn * 30];
        smL[ni][c] = acc;
    } else {
        const int v = tid - 960;
        #pragma unroll
        for (int rep = 0; rep < 2; ++rep) {
            const int w = v + rep * 64;
            if (w < 96) {
                const int ni = w / 3, c = w - ni * 3;
                const int nc = min(n0 + ni, Nn - 1);
                float acc = 0.0f;
                const float* xp = xm + ((size_t)(b * Kn) * Nn + nc) * 3 + c;
                #pragma unroll
                for (int k = 0; k < Kn; ++k) acc += xp[(size_t)k * Nn * 3];
                xsL[ni][c] = acc;
            }
        }
    }
    __syncthreads();

    if (tid < 704) {
        const int ni = tid / 22, e = tid - ni * 22;
        const int n = n0 + ni;
        if (n < Nn) {
            const float u = uv[((size_t)b * Nn + n) * 2 + 0];
            const float v = uv[((size_t)b * Nn + n) * 2 + 1];
            const float w = Wp[(size_t)b * Nn + n];
            const float dxu = cx - u, dyv = cy - v;
            float val;
            if (e < 10)       val = w * (f0 * smL[ni][e] + dxu * smL[ni][20 + e]);
            else if (e < 20)  val = w * (f1 * smL[ni][e] + dyv * smL[ni][e + 10]);
            else if (e == 20) val = w * (-f0 * xsL[ni][0] - dxu * xsL[ni][2]);
            else              val = w * (-f1 * xsL[ni][1] - dyv * xsL[ni][2]);
            pre[((size_t)b * Nn + n) * 22 + e] = val;
        }
    }
}

// ---------------- k_gram: dbuf rows + lower-tri fp64 Gram (2 groups) --------
__global__ __launch_bounds__(1024) void k_gram(
    const float* __restrict__ uv, const float* __restrict__ xm,
    const float* __restrict__ blend, const float* __restrict__ Wp,
    const float* __restrict__ m00, const float* __restrict__ m11,
    const float* __restrict__ m02, const float* __restrict__ m12,
    const float* __restrict__ pre, double* __restrict__ Gpk)
{
    __shared__ float rows[2][16][2][160];   // 80 KB
    const int tid = threadIdx.x;
    const int b = blockIdx.y;
    const int n0 = blockIdx.x * GCH;
    const int nEnd = min(n0 + GCH, Nn);
    const float f0 = m00[b], f1 = m11[b], cx = m02[b], cy = m12[b];

    const bool isB = tid < 384;
    const int bk = tid >> 4, bp = tid & 15;
    const bool isP = (tid >= 384) && (tid < 736);
    const int q = tid - 384;
    const int pp = q / 22, pe = q - pp * 22;

    // FMA role: two groups of 496 threads; group g covers points g*8..g*8+7
    const int g = tid >> 9;         // 0 or 1
    const int t5 = tid & 511;
    const bool isF = t5 < 496;
    int ti = 0, tj = 0;
    if (isF) {
        int t = t5;
        int row = (int)((sqrtf(8.0f * (float)t + 1.0f) - 1.0f) * 0.5f);
        while ((row + 1) * (row + 2) / 2 <= t) ++row;
        while (row * (row + 1) / 2 > t) --row;
        ti = row; tj = t - row * (row + 1) / 2;
    }

    double acc[5][5] = {};
    float pf_x0 = 0, pf_x1 = 0, pf_x2 = 0, pf_bl = 0, pf_u = 0, pf_v = 0, pf_w = 0, pf_pre = 0;

    auto PREFETCH = [&](int rnd) {
        const int nb = n0 + rnd * 16;
        if (isB) {
            const int n = min(nb + bp, Nn - 1);
            const float* xp = xm + ((size_t)(b * Kn + bk) * Nn + n) * 3;
            pf_x0 = xp[0]; pf_x1 = xp[1]; pf_x2 = xp[2];
            pf_bl = blend[n * Kn + bk];
            pf_u = uv[((size_t)b * Nn + n) * 2 + 0];
            pf_v = uv[((size_t)b * Nn + n) * 2 + 1];
            pf_w = Wp[(size_t)b * Nn + n];
        } else if (isP) {
            const int n = min(nb + pp, Nn - 1);
            pf_pre = pre[((size_t)b * Nn + n) * 22 + pe];
        }
    };
    auto BUILD = [&](int rnd, int bufi) {
        const int nb = n0 + rnd * 16;
        if (isB) {
            const int n = nb + bp;
            float* rx = &rows[bufi][bp][0][bk * 6];
            float* ry = &rows[bufi][bp][1][bk * 6];
            if (n < nEnd) {
                const float dxu = cx - pf_u, dyv = cy - pf_v, w = pf_w;
                const float wbl = w * pf_bl;
                rx[0] = w * dxu * pf_x1;
                rx[1] = w * (f0 * pf_x2 - dxu * pf_x0);
                rx[2] = -w * f0 * pf_x1;
                rx[3] = wbl * f0;
                rx[4] = 0.0f;
                rx[5] = wbl * dxu;
                ry[0] = w * (dyv * pf_x1 - f1 * pf_x2);
                ry[1] = -w * dyv * pf_x0;
                ry[2] = w * f1 * pf_x0;
                ry[3] = 0.0f;
                ry[4] = wbl * f1;
                ry[5] = wbl * dyv;
            } else {
                #pragma unroll
                for (int e = 0; e < 6; ++e) { rx[e] = 0.0f; ry[e] = 0.0f; }
            }
        } else if (isP) {
            const int n = nb + pp;
            const float v = (n < nEnd) ? pf_pre : 0.0f;
            if (pe < 10)       rows[bufi][pp][0][144 + pe] = v;
            else if (pe < 20)  rows[bufi][pp][1][134 + pe] = v;
            else if (pe == 20) rows[bufi][pp][0][154] = v;
            else               rows[bufi][pp][1][154] = v;
        }
    };

    // zero pad cols 155..159 of both buffers (never rewritten)
    if (tid < 320) {
        const int bufi = tid / 160, rem = tid - bufi * 160;
        const int p = rem / 10, h = (rem % 10) / 5, c = 155 + rem % 5;
        rows[bufi][p][h][c] = 0.0f;
    }

    PREFETCH(0);
    BUILD(0, 0);
    PREFETCH(1);
    __syncthreads();

    for (int r = 0; r < RNDS; ++r) {
        const int cur = r & 1, nxt = cur ^ 1;
        if (r < RNDS - 1) {
            BUILD(r + 1, nxt);
            if (r < RNDS - 2) PREFETCH(r + 2);
        }
        if (isF) {
            #pragma unroll
            for (int p8 = 0; p8 < 8; ++p8) {
                const int p = (g << 3) + p8;
                #pragma unroll
                for (int h = 0; h < 2; ++h) {
                    const float* rr = &rows[cur][p][h][0];
                    double rv[5], rh[5];
                    #pragma unroll
                    for (int i = 0; i < 5; ++i) rv[i] = (double)rr[ti * 5 + i];
                    #pragma unroll
                    for (int j = 0; j < 5; ++j) rh[j] = (double)rr[tj * 5 + j];
                    #pragma unroll
                    for (int i = 0; i < 5; ++i)
                        #pragma unroll
                        for (int j = 0; j < 5; ++j)
                            acc[i][j] = fma(rv[i], rh[j], acc[i][j]);
                }
            }
        }
        __syncthreads();
    }

    double* Gb = Gpk + (size_t)b * GPK;
    if (isF) {
        if (g == 0) {
            #pragma unroll
            for (int i = 0; i < 5; ++i) {
                const int gi = ti * 5 + i;
                const int base = (gi * (gi + 1)) >> 1;
                #pragma unroll
                for (int j = 0; j < 5; ++j) {
                    const int gj = tj * 5 + j;
                    if (gj <= gi) unsafeAtomicAdd(&Gb[base + gj], acc[i][j]);
                }
            }
        } else {
            #pragma unroll
            for (int i = 4; i >= 0; --i) {
                const int gi = ti * 5 + i;
                const int base = (gi * (gi + 1)) >> 1;
                #pragma unroll
                for (int j = 4; j >= 0; --j) {
                    const int gj = tj * 5 + j;
                    if (gj <= gi) unsafeAtomicAdd(&Gb[base + gj], acc[i][j]);
                }
            }
        }
    }
}

// ---------------- k_solve: single-wave zero-barrier LDL^T + outputs ---------
__global__ __launch_bounds__(64) void k_solve(
    const float* __restrict__ pbeta, const float* __restrict__ vR,
    const double* __restrict__ Gpk, float* __restrict__ out)
{
    __shared__ double tri[11935];
    __shared__ double cv[160];
    __shared__ double dinv[160];
    const int tid = threadIdx.x;          // 0..63, single wave
    const int b = blockIdx.x;
    const double lam2 = 1.0 / 9.0;
    const double* Gb = Gpk + (size_t)b * GPK;

    for (int idx = tid; idx < 11935; idx += 64) tri[idx] = Gb[idx];
    for (int r = tid; r < 154; r += 64) {
        double c0 = Gb[11935 + r];
        if (r >= 144) c0 += lam2 * (double)pbeta[b * 10 + (r - 144)];
        cv[r] = c0;
    }
    __syncthreads();
    if (tid < 10) {
        const int d = 144 + tid;
        tri[((d * (d + 1)) >> 1) + d] += lam2;
    }
    __syncthreads();

    // LDL^T, raw columns, wave-synchronous (no barriers: single wave,
    // in-order LDS pipe + may-alias dynamic indices pin compiler ordering)
    for (int j = 0; j < 153; ++j) {
        const double invd = 1.0 / tri[((j * (j + 1)) >> 1) + j];
        int ii = j + 1 + tid;
        while (ii < 154) {
            const int bi = (ii * (ii + 1)) >> 1;
            const double mij = tri[bi + j] * invd;
            int bk = ((j + 1) * (j + 2)) >> 1;
            for (int kk = j + 1; kk <= ii; ++kk) {
                tri[bi + kk] -= mij * tri[bk + j];   // tri[bk+j]: uniform kk -> LDS broadcast
                bk += kk + 1;
            }
            ii += 64;
        }
    }
    for (int r = tid; r < 154; r += 64)
        dinv[r] = 1.0 / tri[((r * (r + 1)) >> 1) + r];

    // forward + D-scale: cv becomes w = D^-1 L^-1 c
    for (int j = 0; j < 154; ++j) {
        const double wj = cv[j] * dinv[j];
        cv[j] = wj;
        for (int i = j + 1 + tid; i < 154; i += 64)
            cv[i] -= tri[((i * (i + 1)) >> 1) + j] * wj;
    }
    // backward: x[i] = w[i] - dinv[i] * sum_j L_raw[j][i] x[j]
    for (int j = 153; j >= 1; --j) {
        const double xj = cv[j];
        const int bj = (j * (j + 1)) >> 1;
        for (int i = tid; i < j; i += 64)
            cv[i] -= dinv[i] * tri[bj + i] * xj;
    }

    // epilogue: Rodrigues + outputs (float32); same wave, no barrier needed
    if (tid < Kn) {
        const int k = tid;
        const double rxv = cv[6 * k + 0], ryv = cv[6 * k + 1], rzv = cv[6 * k + 2];
        const double t0 = cv[6 * k + 3], t1 = cv[6 * k + 4], t2 = cv[6 * k + 5];
        const double nrm = sqrt(rxv * rxv + ryv * ryv + rzv * rzv);
        const double th = fmax(nrm, 1e-8);
        const double ax = rxv / th, ay = ryv / th, az = rzv / th;
        const double c = cos(th), sn = sin(th), mc = 1.0 - c;
        double R[3][3];
        R[0][0] = c + mc * ax * ax;        R[0][1] = -sn * az + mc * ax * ay; R[0][2] =  sn * ay + mc * ax * az;
        R[1][0] =  sn * az + mc * ay * ax; R[1][1] = c + mc * ay * ay;        R[1][2] = -sn * ax + mc * ay * az;
        R[2][0] = -sn * ay + mc * az * ax; R[2][1] =  sn * ax + mc * az * ay; R[2][2] = c + mc * az * az;

        const float* VRp = vR + ((size_t)(b * Kn + k)) * 16;
        float* oc = out + ((size_t)(b * Kn + k)) * 16;
        #pragma unroll
        for (int r = 0; r < 3; ++r)
            #pragma unroll
            for (int cc = 0; cc < 4; ++cc) {
                const double val = R[r][0] * (double)VRp[0 * 4 + cc]
                                 + R[r][1] * (double)VRp[1 * 4 + cc]
                                 + R[r][2] * (double)VRp[2 * 4 + cc];
                oc[r * 4 + cc] = (float)val;
            }
        #pragma unroll
        for (int cc = 0; cc < 4; ++cc) oc[12 + cc] = VRp[12 + cc];

        float* ot = out + 24576 + ((size_t)(b * Kn + k)) * 3;
        ot[0] = (float)t0; ot[1] = (float)t1; ot[2] = (float)t2;

        float* orp = out + 29824 + ((size_t)(b * Kn + k)) * 9;
        #pragma unroll
        for (int r = 0; r < 3; ++r)
            #pragma unroll
            for (int cc = 0; cc < 3; ++cc)
                orp[r * 3 + cc] = (float)R[r][cc];
    }
    if (tid >= 32 && tid < 42) {
        out[29184 + b * 10 + (tid - 32)] = (float)cv[144 + (tid - 32)];
    }
}

extern "C" void kernel_launch(void* const* d_in, const int* in_sizes, int n_in,
                              void* d_out, int out_size, void* d_ws, size_t ws_size,
                              hipStream_t stream) {
    const float* uv    = (const float*)d_in[0];
    const float* xm    = (const float*)d_in[1];
    const float* bs    = (const float*)d_in[2];
    const float* blend = (const float*)d_in[3];
    const float* Wp    = (const float*)d_in[4];
    const float* m00   = (const float*)d_in[5];
    const float* m11   = (const float*)d_in[6];
    const float* m02   = (const float*)d_in[7];
    const float* m12   = (const float*)d_in[8];
    const float* pbeta = (const float*)d_in[9];
    const float* vRp   = (const float*)d_in[10];
    float* out = (float*)d_out;
    double* Gpk = (double*)d_ws;
    float* pre = (float*)((char*)d_ws + G_BYTES);

    hipMemsetAsync(d_ws, 0, G_BYTES, stream);

    dim3 gP((Nn + 31) / 32, Bn);
    k_pre<<<gP, 1024, 0, stream>>>(uv, xm, bs, Wp, m00, m11, m02, m12, pre);

    dim3 gG(NBLK, Bn);
    k_gram<<<gG, 1024, 0, stream>>>(uv, xm, blend, Wp, m00, m11, m02, m12, pre, Gpk);

    k_solve<<<Bn, 64, 0, stream>>>(pbeta, vRp, Gpk, out);
}

// Round 6
// 458.641 us; speedup vs baseline: 3.4905x; 3.4905x over previous
//
#include <hip/hip_runtime.h>
#include <hip/hip_bf16.h>

#define Bn 64
#define Kn 24
#define Nn 934
#define NBLK 8
#define GCH 117          // points per gram block
#define RNDS 8           // 8 * 16 = 128 >= 117
#define GPK 12090        // 155*156/2 packed lower (row 154 = rhs row)
#define PB 11            // solve panel width
#define NPAN 14          // 14 * 11 = 154

#define G_BYTES ((size_t)Bn * GPK * 8)

__device__ __forceinline__ int rb(int i) { return (i * (i + 1)) >> 1; }

// ---------------- k_pre: stream-reduce b_s_ and xm over K -------------------
__global__ __launch_bounds__(1024) void k_pre(
    const float* __restrict__ uv, const float* __restrict__ xm,
    const float* __restrict__ bs, const float* __restrict__ Wp,
    const float* __restrict__ m00, const float* __restrict__ m11,
    const float* __restrict__ m02, const float* __restrict__ m12,
    float* __restrict__ pre)
{
    __shared__ float smL[32][30];
    __shared__ float xsL[32][3];
    const int tid = threadIdx.x;
    const int b = blockIdx.y;
    const int n0 = blockIdx.x * 32;
    const float f0 = m00[b], f1 = m11[b], cx = m02[b], cy = m12[b];

    if (tid < 960) {
        const int ni = tid / 30, c = tid - ni * 30;
        const int nc = min(n0 + ni, Nn - 1);
        float acc = 0.0f;
        const float* bp = bs + ((size_t)(b * Kn) * Nn + nc) * 30 + c;
        #pragma unroll
        for (int k = 0; k < Kn; ++k) acc += bp[(size_t)k * Nn * 30];
        smL[ni][c] = acc;
    } else {
        const int v = tid - 960;
        #pragma unroll
        for (int rep = 0; rep < 2; ++rep) {
            const int w = v + rep * 64;
            if (w < 96) {
                const int ni = w / 3, c = w - ni * 3;
                const int nc = min(n0 + ni, Nn - 1);
                float acc = 0.0f;
                const float* xp = xm + ((size_t)(b * Kn) * Nn + nc) * 3 + c;
                #pragma unroll
                for (int k = 0; k < Kn; ++k) acc += xp[(size_t)k * Nn * 3];
                xsL[ni][c] = acc;
            }
        }
    }
    __syncthreads();

    if (tid < 704) {
        const int ni = tid / 22, e = tid - ni * 22;
        const int n = n0 + ni;
        if (n < Nn) {
            const float u = uv[((size_t)b * Nn + n) * 2 + 0];
            const float v = uv[((size_t)b * Nn + n) * 2 + 1];
            const float w = Wp[(size_t)b * Nn + n];
            const float dxu = cx - u, dyv = cy - v;
            float val;
            if (e < 10)       val = w * (f0 * smL[ni][e] + dxu * smL[ni][20 + e]);
            else if (e < 20)  val = w * (f1 * smL[ni][e] + dyv * smL[ni][e + 10]);
            else if (e == 20) val = w * (-f0 * xsL[ni][0] - dxu * xsL[ni][2]);
            else              val = w * (-f1 * xsL[ni][1] - dyv * xsL[ni][2]);
            pre[((size_t)b * Nn + n) * 22 + e] = val;
        }
    }
}

// ---------------- k_gram: dbuf rows + lower-tri fp64 Gram (round-4 form) ----
__global__ __launch_bounds__(1024) void k_gram(
    const float* __restrict__ uv, const float* __restrict__ xm,
    const float* __restrict__ blend, const float* __restrict__ Wp,
    const float* __restrict__ m00, const float* __restrict__ m11,
    const float* __restrict__ m02, const float* __restrict__ m12,
    const float* __restrict__ pre, double* __restrict__ Gpk)
{
    __shared__ float rows[2][16][2][160];   // 80 KB
    const int tid = threadIdx.x;
    const int b = blockIdx.y;
    const int n0 = blockIdx.x * GCH;
    const int nEnd = min(n0 + GCH, Nn);
    const float f0 = m00[b], f1 = m11[b], cx = m02[b], cy = m12[b];

    const bool isB = tid < 384;
    const int bk = tid >> 4, bp = tid & 15;
    const bool isP = (tid >= 384) && (tid < 736);
    const int q = tid - 384;
    const int pp = q / 22, pe = q - pp * 22;

    int ti = 0, tj = 0;
    if (tid < 496) {
        int t = tid;
        int row = (int)((sqrtf(8.0f * (float)t + 1.0f) - 1.0f) * 0.5f);
        while ((row + 1) * (row + 2) / 2 <= t) ++row;
        while (row * (row + 1) / 2 > t) --row;
        ti = row; tj = t - row * (row + 1) / 2;
    }

    double acc[5][5] = {};
    float pf_x0 = 0, pf_x1 = 0, pf_x2 = 0, pf_bl = 0, pf_u = 0, pf_v = 0, pf_w = 0, pf_pre = 0;

    auto PREFETCH = [&](int rnd) {
        const int nb = n0 + rnd * 16;
        if (isB) {
            const int n = min(nb + bp, Nn - 1);
            const float* xp = xm + ((size_t)(b * Kn + bk) * Nn + n) * 3;
            pf_x0 = xp[0]; pf_x1 = xp[1]; pf_x2 = xp[2];
            pf_bl = blend[n * Kn + bk];
            pf_u = uv[((size_t)b * Nn + n) * 2 + 0];
            pf_v = uv[((size_t)b * Nn + n) * 2 + 1];
            pf_w = Wp[(size_t)b * Nn + n];
        } else if (isP) {
            const int n = min(nb + pp, Nn - 1);
            pf_pre = pre[((size_t)b * Nn + n) * 22 + pe];
        }
    };
    auto BUILD = [&](int rnd, int bufi) {
        const int nb = n0 + rnd * 16;
        if (isB) {
            const int n = nb + bp;
            float* rx = &rows[bufi][bp][0][bk * 6];
            float* ry = &rows[bufi][bp][1][bk * 6];
            if (n < nEnd) {
                const float dxu = cx - pf_u, dyv = cy - pf_v, w = pf_w;
                const float wbl = w * pf_bl;
                rx[0] = w * dxu * pf_x1;
                rx[1] = w * (f0 * pf_x2 - dxu * pf_x0);
                rx[2] = -w * f0 * pf_x1;
                rx[3] = wbl * f0;
                rx[4] = 0.0f;
                rx[5] = wbl * dxu;
                ry[0] = w * (dyv * pf_x1 - f1 * pf_x2);
                ry[1] = -w * dyv * pf_x0;
                ry[2] = w * f1 * pf_x0;
                ry[3] = 0.0f;
                ry[4] = wbl * f1;
                ry[5] = wbl * dyv;
            } else {
                #pragma unroll
                for (int e = 0; e < 6; ++e) { rx[e] = 0.0f; ry[e] = 0.0f; }
            }
        } else if (isP) {
            const int n = nb + pp;
            const float v = (n < nEnd) ? pf_pre : 0.0f;
            if (pe < 10)       rows[bufi][pp][0][144 + pe] = v;
            else if (pe < 20)  rows[bufi][pp][1][134 + pe] = v;
            else if (pe == 20) rows[bufi][pp][0][154] = v;
            else               rows[bufi][pp][1][154] = v;
        }
    };

    if (tid < 320) {
        const int bufi = tid / 160, rem = tid - bufi * 160;
        const int p = rem / 10, h = (rem % 10) / 5, c = 155 + rem % 5;
        rows[bufi][p][h][c] = 0.0f;
    }

    PREFETCH(0);
    BUILD(0, 0);
    PREFETCH(1);
    __syncthreads();

    for (int r = 0; r < RNDS; ++r) {
        const int cur = r & 1, nxt = cur ^ 1;
        if (r < RNDS - 1) {
            BUILD(r + 1, nxt);
            if (r < RNDS - 2) PREFETCH(r + 2);
        }
        if (tid < 496) {
            for (int p = 0; p < 16; ++p) {
                #pragma unroll
                for (int h = 0; h < 2; ++h) {
                    const float* rr = &rows[cur][p][h][0];
                    double rv[5], rh[5];
                    #pragma unroll
                    for (int i = 0; i < 5; ++i) rv[i] = (double)rr[ti * 5 + i];
                    #pragma unroll
                    for (int j = 0; j < 5; ++j) rh[j] = (double)rr[tj * 5 + j];
                    #pragma unroll
                    for (int i = 0; i < 5; ++i)
                        #pragma unroll
                        for (int j = 0; j < 5; ++j)
                            acc[i][j] = fma(rv[i], rh[j], acc[i][j]);
                }
            }
        }
        __syncthreads();
    }

    double* Gb = Gpk + (size_t)b * GPK;
    if (tid < 496) {
        #pragma unroll
        for (int i = 0; i < 5; ++i) {
            const int gi = ti * 5 + i;
            const int base = rb(gi);
            #pragma unroll
            for (int j = 0; j < 5; ++j) {
                const int gj = tj * 5 + j;
                if (gj <= gi) unsafeAtomicAdd(&Gb[base + gj], acc[i][j]);
            }
        }
    }
}

// ---------------- k_solve: blocked LDL^T (panel=11) + blocked subs ----------
__global__ __launch_bounds__(256) void k_solve(
    const float* __restrict__ pbeta, const float* __restrict__ vR,
    const double* __restrict__ Gpk, float* __restrict__ out)
{
    __shared__ double tri[11935];     // packed lower, raw columns
    __shared__ double cv[160];
    __shared__ double dinv[160];
    __shared__ double Pp[143][PB];    // scaled panel rows
    __shared__ double Qq[143][PB];    // raw panel rows
    const int tid = threadIdx.x;
    const int b = blockIdx.x;
    const double lam2 = 1.0 / 9.0;
    const double* Gb = Gpk + (size_t)b * GPK;

    for (int idx = tid; idx < 11935; idx += 256) tri[idx] = Gb[idx];
    for (int r = tid; r < 154; r += 256) {
        double c0v = Gb[11935 + r];
        if (r >= 144) c0v += lam2 * (double)pbeta[b * 10 + (r - 144)];
        cv[r] = c0v;
    }
    __syncthreads();
    if (tid < 10) { const int d = 144 + tid; tri[rb(d) + d] += lam2; }
    __syncthreads();

    // ================= factorization =================
    for (int p = 0; p < NPAN; ++p) {
        const int c0 = p * PB, r0 = c0 + PB, m = 154 - r0;

        // ---- phase 1: diag block factor, redundant in registers ----
        double dblk[66], dl[PB];
        #pragma unroll
        for (int r = 0; r < PB; ++r) {
            const int baser = rb(c0 + r) + c0;
            #pragma unroll
            for (int c = 0; c <= r; ++c) dblk[r * (r + 1) / 2 + c] = tri[baser + c];
        }
        #pragma unroll
        for (int j = 0; j < PB; ++j) {
            const double invd = 1.0 / dblk[j * (j + 1) / 2 + j];
            dl[j] = invd;
            #pragma unroll
            for (int r = j + 1; r < PB; ++r) {
                const double mr = dblk[r * (r + 1) / 2 + j] * invd;
                #pragma unroll
                for (int c = j + 1; c <= r; ++c)
                    dblk[r * (r + 1) / 2 + c] -= mr * dblk[c * (c + 1) / 2 + j];
            }
        }
        #pragma unroll
        for (int r = 0; r < PB; ++r) {
            const int baser = rb(c0 + r) + c0;
            #pragma unroll
            for (int c = 0; c <= r; ++c) tri[baser + c] = dblk[r * (r + 1) / 2 + c];
        }
        #pragma unroll
        for (int j = 0; j < PB; ++j) dinv[c0 + j] = dl[j];

        if (m > 0) {
            // ---- phase 2: panel rows (1 row / thread) ----
            for (int i = r0 + tid; i < 154; i += 256) {
                const int ip = i - r0;
                const int base = rb(i) + c0;
                double a[PB], bb[PB];
                #pragma unroll
                for (int k = 0; k < PB; ++k) a[k] = tri[base + k];
                #pragma unroll
                for (int t = 0; t < PB; ++t) {
                    const double bt = a[t] * dl[t];
                    bb[t] = bt;
                    #pragma unroll
                    for (int k = t + 1; k < PB; ++k)
                        a[k] -= bt * dblk[k * (k + 1) / 2 + t];
                }
                #pragma unroll
                for (int k = 0; k < PB; ++k) {
                    tri[base + k] = a[k]; Pp[ip][k] = bb[k]; Qq[ip][k] = a[k];
                }
            }
            __syncthreads();
            // ---- phase 3: trailing rank-11 update ----
            const int tot = (m * (m + 1)) >> 1;
            for (int e = tid; e < tot; e += 256) {
                int row = (int)((sqrtf(8.0f * (float)e + 1.0f) - 1.0f) * 0.5f);
                while ((row + 1) * (row + 2) / 2 <= e) ++row;
                while (row * (row + 1) / 2 > e) --row;
                const int col = e - ((row * (row + 1)) >> 1);
                double s = 0.0;
                #pragma unroll
                for (int k = 0; k < PB; ++k) s += Pp[row][k] * Qq[col][k];
                tri[rb(r0 + row) + r0 + col] -= s;
            }
        }
        __syncthreads();
    }

    // ================= forward substitution (blocked) =================
    for (int p = 0; p < NPAN; ++p) {
        const int c0 = p * PB, r0 = c0 + PB;
        double w[PB], sb[66], dl[PB];
        #pragma unroll
        for (int r = 0; r < PB; ++r) {
            const int baser = rb(c0 + r) + c0;
            #pragma unroll
            for (int c = 0; c < r; ++c) sb[r * (r + 1) / 2 + c] = tri[baser + c];
            dl[r] = dinv[c0 + r];
            w[r] = cv[c0 + r];
        }
        #pragma unroll
        for (int t = 0; t < PB; ++t) {
            w[t] *= dl[t];
            #pragma unroll
            for (int k = t + 1; k < PB; ++k) w[k] -= sb[k * (k + 1) / 2 + t] * w[t];
        }
        #pragma unroll
        for (int t = 0; t < PB; ++t) cv[c0 + t] = w[t];
        for (int i = r0 + tid; i < 154; i += 256) {
            const int base = rb(i) + c0;
            double s = 0.0;
            #pragma unroll
            for (int k = 0; k < PB; ++k) s += tri[base + k] * w[k];
            cv[i] -= s;
        }
        __syncthreads();
    }

    // ================= backward substitution (blocked) =================
    for (int p = NPAN - 1; p >= 0; --p) {
        const int c0 = p * PB;
        double x[PB], sb[66], dl[PB];
        #pragma unroll
        for (int r = 0; r < PB; ++r) {
            const int baser = rb(c0 + r) + c0;
            #pragma unroll
            for (int c = 0; c < r; ++c) sb[r * (r + 1) / 2 + c] = tri[baser + c];
            dl[r] = dinv[c0 + r];
            x[r] = cv[c0 + r];
        }
        #pragma unroll
        for (int j = PB - 1; j >= 1; --j) {
            #pragma unroll
            for (int i = 0; i < j; ++i)
                x[i] -= dl[i] * sb[j * (j + 1) / 2 + i] * x[j];
        }
        #pragma unroll
        for (int r = 0; r < PB; ++r) cv[c0 + r] = x[r];
        for (int i = tid; i < c0; i += 256) {
            double s = 0.0;
            #pragma unroll
            for (int jj = 0; jj < PB; ++jj) s += tri[rb(c0 + jj) + i] * x[jj];
            cv[i] -= dinv[i] * s;
        }
        __syncthreads();
    }

    // ================= epilogue: Rodrigues + outputs (float32) ==========
    if (tid < Kn) {
        const int k = tid;
        const double rxv = cv[6 * k + 0], ryv = cv[6 * k + 1], rzv = cv[6 * k + 2];
        const double t0 = cv[6 * k + 3], t1 = cv[6 * k + 4], t2 = cv[6 * k + 5];
        const double nrm = sqrt(rxv * rxv + ryv * ryv + rzv * rzv);
        const double th = fmax(nrm, 1e-8);
        const double ax = rxv / th, ay = ryv / th, az = rzv / th;
        const double c = cos(th), sn = sin(th), mc = 1.0 - c;
        double R[3][3];
        R[0][0] = c + mc * ax * ax;        R[0][1] = -sn * az + mc * ax * ay; R[0][2] =  sn * ay + mc * ax * az;
        R[1][0] =  sn * az + mc * ay * ax; R[1][1] = c + mc * ay * ay;        R[1][2] = -sn * ax + mc * ay * az;
        R[2][0] = -sn * ay + mc * az * ax; R[2][1] =  sn * ax + mc * az * ay; R[2][2] = c + mc * az * az;

        const float* VRp = vR + ((size_t)(b * Kn + k)) * 16;
        float* oc = out + ((size_t)(b * Kn + k)) * 16;
        #pragma unroll
        for (int r = 0; r < 3; ++r)
            #pragma unroll
            for (int cc = 0; cc < 4; ++cc) {
                const double val = R[r][0] * (double)VRp[0 * 4 + cc]
                                 + R[r][1] * (double)VRp[1 * 4 + cc]
                                 + R[r][2] * (double)VRp[2 * 4 + cc];
                oc[r * 4 + cc] = (float)val;
            }
        #pragma unroll
        for (int cc = 0; cc < 4; ++cc) oc[12 + cc] = VRp[12 + cc];

        float* ot = out + 24576 + ((size_t)(b * Kn + k)) * 3;
        ot[0] = (float)t0; ot[1] = (float)t1; ot[2] = (float)t2;

        float* orp = out + 29824 + ((size_t)(b * Kn + k)) * 9;
        #pragma unroll
        for (int r = 0; r < 3; ++r)
            #pragma unroll
            for (int cc = 0; cc < 3; ++cc)
                orp[r * 3 + cc] = (float)R[r][cc];
    }
    if (tid >= 32 && tid < 42) {
        out[29184 + b * 10 + (tid - 32)] = (float)cv[144 + (tid - 32)];
    }
}

extern "C" void kernel_launch(void* const* d_in, const int* in_sizes, int n_in,
                              void* d_out, int out_size, void* d_ws, size_t ws_size,
                              hipStream_t stream) {
    const float* uv    = (const float*)d_in[0];
    const float* xm    = (const float*)d_in[1];
    const float* bs    = (const float*)d_in[2];
    const float* blend = (const float*)d_in[3];
    const float* Wp    = (const float*)d_in[4];
    const float* m00   = (const float*)d_in[5];
    const float* m11   = (const float*)d_in[6];
    const float* m02   = (const float*)d_in[7];
    const float* m12   = (const float*)d_in[8];
    const float* pbeta = (const float*)d_in[9];
    const float* vRp   = (const float*)d_in[10];
    float* out = (float*)d_out;
    double* Gpk = (double*)d_ws;
    float* pre = (float*)((char*)d_ws + G_BYTES);

    hipMemsetAsync(d_ws, 0, G_BYTES, stream);

    dim3 gP((Nn + 31) / 32, Bn);
    k_pre<<<gP, 1024, 0, stream>>>(uv, xm, bs, Wp, m00, m11, m02, m12, pre);

    dim3 gG(NBLK, Bn);
    k_gram<<<gG, 1024, 0, stream>>>(uv, xm, blend, Wp, m00, m11, m02, m12, pre, Gpk);

    k_solve<<<Bn, 256, 0, stream>>>(pbeta, vRp, Gpk, out);
}

// Round 8
// 431.007 us; speedup vs baseline: 3.7143x; 1.0641x over previous
//
#include <hip/hip_runtime.h>
#include <hip/hip_bf16.h>

#define Bn 64
#define Kn 24
#define Nn 934
#define NBLK 8
#define GCH 117          // points per gram block
#define RNDS 8           // 8 * 16 = 128 >= 117
#define GPK 12090        // 155*156/2 packed lower (row 154 = rhs row)
#define PB 11            // solve panel width
#define NPAN 14          // 14 * 11 = 154
#define ST 512           // k_solve threads

#define G_BYTES ((size_t)Bn * GPK * 8)

__device__ __forceinline__ int rb(int i) { return (i * (i + 1)) >> 1; }

// ---------------- k_pre: stream-reduce b_s_ and xm over K -------------------
__global__ __launch_bounds__(1024) void k_pre(
    const float* __restrict__ uv, const float* __restrict__ xm,
    const float* __restrict__ bs, const float* __restrict__ Wp,
    const float* __restrict__ m00, const float* __restrict__ m11,
    const float* __restrict__ m02, const float* __restrict__ m12,
    float* __restrict__ pre)
{
    __shared__ float smL[32][30];
    __shared__ float xsL[32][3];
    const int tid = threadIdx.x;
    const int b = blockIdx.y;
    const int n0 = blockIdx.x * 32;
    const float f0 = m00[b], f1 = m11[b], cx = m02[b], cy = m12[b];

    if (tid < 960) {
        const int ni = tid / 30, c = tid - ni * 30;
        const int nc = min(n0 + ni, Nn - 1);
        float acc = 0.0f;
        const float* bp = bs + ((size_t)(b * Kn) * Nn + nc) * 30 + c;
        #pragma unroll
        for (int k = 0; k < Kn; ++k) acc += bp[(size_t)k * Nn * 30];
        smL[ni][c] = acc;
    } else {
        const int v = tid - 960;
        #pragma unroll
        for (int rep = 0; rep < 2; ++rep) {
            const int w = v + rep * 64;
            if (w < 96) {
                const int ni = w / 3, c = w - ni * 3;
                const int nc = min(n0 + ni, Nn - 1);
                float acc = 0.0f;
                const float* xp = xm + ((size_t)(b * Kn) * Nn + nc) * 3 + c;
                #pragma unroll
                for (int k = 0; k < Kn; ++k) acc += xp[(size_t)k * Nn * 3];
                xsL[ni][c] = acc;
            }
        }
    }
    __syncthreads();

    if (tid < 704) {
        const int ni = tid / 22, e = tid - ni * 22;
        const int n = n0 + ni;
        if (n < Nn) {
            const float u = uv[((size_t)b * Nn + n) * 2 + 0];
            const float v = uv[((size_t)b * Nn + n) * 2 + 1];
            const float w = Wp[(size_t)b * Nn + n];
            const float dxu = cx - u, dyv = cy - v;
            float val;
            if (e < 10)       val = w * (f0 * smL[ni][e] + dxu * smL[ni][20 + e]);
            else if (e < 20)  val = w * (f1 * smL[ni][e] + dyv * smL[ni][e + 10]);
            else if (e == 20) val = w * (-f0 * xsL[ni][0] - dxu * xsL[ni][2]);
            else              val = w * (-f1 * xsL[ni][1] - dyv * xsL[ni][2]);
            pre[((size_t)b * Nn + n) * 22 + e] = val;
        }
    }
}

// ---------------- k_gram: wave-disjoint roles: FMA | build | pre ------------
__global__ __launch_bounds__(1024) void k_gram(
    const float* __restrict__ uv, const float* __restrict__ xm,
    const float* __restrict__ blend, const float* __restrict__ Wp,
    const float* __restrict__ m00, const float* __restrict__ m11,
    const float* __restrict__ m02, const float* __restrict__ m12,
    const float* __restrict__ pre, double* __restrict__ Gpk)
{
    __shared__ float rows[2][16][2][160];   // 40 KB
    const int tid = threadIdx.x;
    const int b = blockIdx.y;
    const int n0 = blockIdx.x * GCH;
    const int nEnd = min(n0 + GCH, Nn);
    const float f0 = m00[b], f1 = m11[b], cx = m02[b], cy = m12[b];

    // roles (wave-disjoint):
    const bool isF = tid < 512;                       // waves 0-7: FMA (496 active)
    const bool isB = (tid >= 512) && (tid < 896);     // waves 8-13: builders
    const bool isP = tid >= 896;                      // waves 14-15: pre-writers
    const int bk = (tid - 512) >> 4, bp = (tid - 512) & 15;
    const int q0 = tid - 896;                         // 0..127

    int ti = 0, tj = 0;
    if (tid < 496) {
        int t = tid;
        int row = (int)((sqrtf(8.0f * (float)t + 1.0f) - 1.0f) * 0.5f);
        while ((row + 1) * (row + 2) / 2 <= t) ++row;
        while (row * (row + 1) / 2 > t) --row;
        ti = row; tj = t - row * (row + 1) / 2;
    }

    double acc[5][5] = {};
    float pf_x0 = 0, pf_x1 = 0, pf_x2 = 0, pf_bl = 0, pf_u = 0, pf_v = 0, pf_w = 0;
    float pf_pre[3] = {0, 0, 0};

    auto PREFETCH = [&](int rnd) {
        const int nb = n0 + rnd * 16;
        if (isB) {
            const int n = min(nb + bp, Nn - 1);
            const float* xp = xm + ((size_t)(b * Kn + bk) * Nn + n) * 3;
            pf_x0 = xp[0]; pf_x1 = xp[1]; pf_x2 = xp[2];
            pf_bl = blend[n * Kn + bk];
            pf_u = uv[((size_t)b * Nn + n) * 2 + 0];
            pf_v = uv[((size_t)b * Nn + n) * 2 + 1];
            pf_w = Wp[(size_t)b * Nn + n];
        } else if (isP) {
            #pragma unroll
            for (int s = 0; s < 3; ++s) {
                const int e = q0 + s * 128;
                if (e < 352) {
                    const int pp = e / 22, pe = e - pp * 22;
                    const int n = min(nb + pp, Nn - 1);
                    pf_pre[s] = pre[((size_t)b * Nn + n) * 22 + pe];
                }
            }
        }
    };
    auto BUILD = [&](int rnd, int bufi) {
        const int nb = n0 + rnd * 16;
        if (isB) {
            const int n = nb + bp;
            float* rx = &rows[bufi][bp][0][bk * 6];
            float* ry = &rows[bufi][bp][1][bk * 6];
            if (n < nEnd) {
                const float dxu = cx - pf_u, dyv = cy - pf_v, w = pf_w;
                const float wbl = w * pf_bl;
                rx[0] = w * dxu * pf_x1;
                rx[1] = w * (f0 * pf_x2 - dxu * pf_x0);
                rx[2] = -w * f0 * pf_x1;
                rx[3] = wbl * f0;
                rx[4] = 0.0f;
                rx[5] = wbl * dxu;
                ry[0] = w * (dyv * pf_x1 - f1 * pf_x2);
                ry[1] = -w * dyv * pf_x0;
                ry[2] = w * f1 * pf_x0;
                ry[3] = 0.0f;
                ry[4] = wbl * f1;
                ry[5] = wbl * dyv;
            } else {
                #pragma unroll
                for (int e = 0; e < 6; ++e) { rx[e] = 0.0f; ry[e] = 0.0f; }
            }
        } else if (isP) {
            #pragma unroll
            for (int s = 0; s < 3; ++s) {
                const int e = q0 + s * 128;
                if (e < 352) {
                    const int pp = e / 22, pe = e - pp * 22;
                    const int n = nb + pp;
                    const float v = (n < nEnd) ? pf_pre[s] : 0.0f;
                    if (pe < 10)       rows[bufi][pp][0][144 + pe] = v;
                    else if (pe < 20)  rows[bufi][pp][1][134 + pe] = v;
                    else if (pe == 20) rows[bufi][pp][0][154] = v;
                    else               rows[bufi][pp][1][154] = v;
                }
            }
        }
    };

    // zero pad cols 155..159 of both buffers (never rewritten)
    if (tid < 320) {
        const int bufi = tid / 160, rem = tid - bufi * 160;
        const int p = rem / 10, h = (rem % 10) / 5, c = 155 + rem % 5;
        rows[bufi][p][h][c] = 0.0f;
    }

    PREFETCH(0);
    BUILD(0, 0);
    PREFETCH(1);
    __syncthreads();

    for (int r = 0; r < RNDS; ++r) {
        const int cur = r & 1, nxt = cur ^ 1;
        if (isF) {
            if (tid < 496) {
                for (int p = 0; p < 16; ++p) {
                    #pragma unroll
                    for (int h = 0; h < 2; ++h) {
                        const float* rr = &rows[cur][p][h][0];
                        double rv[5], rh[5];
                        #pragma unroll
                        for (int i = 0; i < 5; ++i) rv[i] = (double)rr[ti * 5 + i];
                        #pragma unroll
                        for (int j = 0; j < 5; ++j) rh[j] = (double)rr[tj * 5 + j];
                        #pragma unroll
                        for (int i = 0; i < 5; ++i)
                            #pragma unroll
                            for (int j = 0; j < 5; ++j)
                                acc[i][j] = fma(rv[i], rh[j], acc[i][j]);
                    }
                }
            }
        } else {
            if (r < RNDS - 1) {
                BUILD(r + 1, nxt);
                if (r < RNDS - 2) PREFETCH(r + 2);
            }
        }
        __syncthreads();
    }

    double* Gb = Gpk + (size_t)b * GPK;
    if (tid < 496) {
        #pragma unroll
        for (int i = 0; i < 5; ++i) {
            const int gi = ti * 5 + i;
            const int base = rb(gi);
            #pragma unroll
            for (int j = 0; j < 5; ++j) {
                const int gj = tj * 5 + j;
                if (gj <= gi) unsafeAtomicAdd(&Gb[base + gj], acc[i][j]);
            }
        }
    }
}

// ---------------- k_solve: blocked LDL^T, race-free redundant phases --------
__global__ __launch_bounds__(ST) void k_solve(
    const float* __restrict__ pbeta, const float* __restrict__ vR,
    const double* __restrict__ Gpk, float* __restrict__ out)
{
    __shared__ double tri[11935];     // packed lower, raw columns
    __shared__ double cv[160];
    __shared__ double dinv[160];
    __shared__ double Pp[143][PB];    // scaled panel rows
    __shared__ double Qq[143][PB];    // raw panel rows
    const int tid = threadIdx.x;
    const int b = blockIdx.x;
    const double lam2 = 1.0 / 9.0;
    const double* Gb = Gpk + (size_t)b * GPK;

    for (int idx = tid; idx < 11935; idx += ST) tri[idx] = Gb[idx];
    for (int r = tid; r < 154; r += ST) {
        double c0v = Gb[11935 + r];
        if (r >= 144) c0v += lam2 * (double)pbeta[b * 10 + (r - 144)];
        cv[r] = c0v;
    }
    __syncthreads();
    if (tid < 10) { const int d = 144 + tid; tri[rb(d) + d] += lam2; }
    __syncthreads();

    // ================= factorization =================
    for (int p = 0; p < NPAN; ++p) {
        const int c0 = p * PB, r0 = c0 + PB, m = 154 - r0;

        // ---- phase 1: diag block factor, redundant in registers ----
        double dblk[66], dl[PB];
        #pragma unroll
        for (int r = 0; r < PB; ++r) {
            const int baser = rb(c0 + r) + c0;
            #pragma unroll
            for (int c = 0; c <= r; ++c) dblk[r * (r + 1) / 2 + c] = tri[baser + c];
        }
        __syncthreads();   // ALL loads done before anyone writes back
        #pragma unroll
        for (int j = 0; j < PB; ++j) {
            const double invd = 1.0 / dblk[j * (j + 1) / 2 + j];
            dl[j] = invd;
            #pragma unroll
            for (int r = j + 1; r < PB; ++r) {
                const double mr = dblk[r * (r + 1) / 2 + j] * invd;
                #pragma unroll
                for (int c = j + 1; c <= r; ++c)
                    dblk[r * (r + 1) / 2 + c] -= mr * dblk[c * (c + 1) / 2 + j];
            }
        }
        if (tid == 0) {   // single writer: no read/write race
            #pragma unroll
            for (int r = 0; r < PB; ++r) {
                const int baser = rb(c0 + r) + c0;
                #pragma unroll
                for (int c = 0; c <= r; ++c) tri[baser + c] = dblk[r * (r + 1) / 2 + c];
            }
            #pragma unroll
            for (int j = 0; j < PB; ++j) dinv[c0 + j] = dl[j];
        }

        if (m > 0) {
            // ---- phase 2: panel rows (1 row / thread, own regs) ----
            for (int i = r0 + tid; i < 154; i += ST) {
                const int ip = i - r0;
                const int base = rb(i) + c0;
                double a[PB], bb[PB];
                #pragma unroll
                for (int k = 0; k < PB; ++k) a[k] = tri[base + k];
                #pragma unroll
                for (int t = 0; t < PB; ++t) {
                    const double bt = a[t] * dl[t];
                    bb[t] = bt;
                    #pragma unroll
                    for (int k = t + 1; k < PB; ++k)
                        a[k] -= bt * dblk[k * (k + 1) / 2 + t];
                }
                #pragma unroll
                for (int k = 0; k < PB; ++k) {
                    tri[base + k] = a[k]; Pp[ip][k] = bb[k]; Qq[ip][k] = a[k];
                }
            }
            __syncthreads();
            // ---- phase 3: trailing rank-11 update ----
            const int tot = (m * (m + 1)) >> 1;
            for (int e = tid; e < tot; e += ST) {
                int row = (int)((sqrtf(8.0f * (float)e + 1.0f) - 1.0f) * 0.5f);
                while ((row + 1) * (row + 2) / 2 <= e) ++row;
                while (row * (row + 1) / 2 > e) --row;
                const int col = e - ((row * (row + 1)) >> 1);
                double s = 0.0;
                #pragma unroll
                for (int k = 0; k < PB; ++k) s += Pp[row][k] * Qq[col][k];
                tri[rb(r0 + row) + r0 + col] -= s;
            }
        }
        __syncthreads();
    }

    // ================= forward substitution (blocked, race-free) ========
    for (int p = 0; p < NPAN; ++p) {
        const int c0 = p * PB, r0 = c0 + PB;
        double w[PB], sb[66], dl[PB];
        #pragma unroll
        for (int r = 0; r < PB; ++r) {
            const int baser = rb(c0 + r) + c0;
            #pragma unroll
            for (int c = 0; c < r; ++c) sb[r * (r + 1) / 2 + c] = tri[baser + c];
            dl[r] = dinv[c0 + r];
            w[r] = cv[c0 + r];
        }
        __syncthreads();   // ALL reads done before cv[c0..] overwritten
        #pragma unroll
        for (int t = 0; t < PB; ++t) {
            w[t] *= dl[t];
            #pragma unroll
            for (int k = t + 1; k < PB; ++k) w[k] -= sb[k * (k + 1) / 2 + t] * w[t];
        }
        if (tid == 0) {
            #pragma unroll
            for (int t = 0; t < PB; ++t) cv[c0 + t] = w[t];
        }
        for (int i = r0 + tid; i < 154; i += ST) {
            const int base = rb(i) + c0;
            double s = 0.0;
            #pragma unroll
            for (int k = 0; k < PB; ++k) s += tri[base + k] * w[k];
            cv[i] -= s;
        }
        __syncthreads();
    }

    // ================= backward substitution (blocked, race-free) =======
    for (int p = NPAN - 1; p >= 0; --p) {
        const int c0 = p * PB;
        double x[PB], sb[66], dl[PB];
        #pragma unroll
        for (int r = 0; r < PB; ++r) {
            const int baser = rb(c0 + r) + c0;
            #pragma unroll
            for (int c = 0; c < r; ++c) sb[r * (r + 1) / 2 + c] = tri[baser + c];
            dl[r] = dinv[c0 + r];
            x[r] = cv[c0 + r];
        }
        __syncthreads();   // ALL reads done before cv[c0..] overwritten
        #pragma unroll
        for (int j = PB - 1; j >= 1; --j) {
            #pragma unroll
            for (int i = 0; i < j; ++i)
                x[i] -= dl[i] * sb[j * (j + 1) / 2 + i] * x[j];
        }
        if (tid == 0) {
            #pragma unroll
            for (int r = 0; r < PB; ++r) cv[c0 + r] = x[r];
        }
        for (int i = tid; i < c0; i += ST) {
            double s = 0.0;
            #pragma unroll
            for (int jj = 0; jj < PB; ++jj) s += tri[rb(c0 + jj) + i] * x[jj];
            cv[i] -= dinv[i] * s;
        }
        __syncthreads();
    }

    // ================= epilogue: Rodrigues + outputs (float32) ==========
    if (tid < Kn) {
        const int k = tid;
        const double rxv = cv[6 * k + 0], ryv = cv[6 * k + 1], rzv = cv[6 * k + 2];
        const double t0 = cv[6 * k + 3], t1 = cv[6 * k + 4], t2 = cv[6 * k + 5];
        const double nrm = sqrt(rxv * rxv + ryv * ryv + rzv * rzv);
        const double th = fmax(nrm, 1e-8);
        const double ax = rxv / th, ay = ryv / th, az = rzv / th;
        const double c = cos(th), sn = sin(th), mc = 1.0 - c;
        double R[3][3];
        R[0][0] = c + mc * ax * ax;        R[0][1] = -sn * az + mc * ax * ay; R[0][2] =  sn * ay + mc * ax * az;
        R[1][0] =  sn * az + mc * ay * ax; R[1][1] = c + mc * ay * ay;        R[1][2] = -sn * ax + mc * ay * az;
        R[2][0] = -sn * ay + mc * az * ax; R[2][1] =  sn * ax + mc * az * ay; R[2][2] = c + mc * az * az;

        const float* VRp = vR + ((size_t)(b * Kn + k)) * 16;
        float* oc = out + ((size_t)(b * Kn + k)) * 16;
        #pragma unroll
        for (int r = 0; r < 3; ++r)
            #pragma unroll
            for (int cc = 0; cc < 4; ++cc) {
                const double val = R[r][0] * (double)VRp[0 * 4 + cc]
                                 + R[r][1] * (double)VRp[1 * 4 + cc]
                                 + R[r][2] * (double)VRp[2 * 4 + cc];
                oc[r * 4 + cc] = (float)val;
            }
        #pragma unroll
        for (int cc = 0; cc < 4; ++cc) oc[12 + cc] = VRp[12 + cc];

        float* ot = out + 24576 + ((size_t)(b * Kn + k)) * 3;
        ot[0] = (float)t0; ot[1] = (float)t1; ot[2] = (float)t2;

        float* orp = out + 29824 + ((size_t)(b * Kn + k)) * 9;
        #pragma unroll
        for (int r = 0; r < 3; ++r)
            #pragma unroll
            for (int cc = 0; cc < 3; ++cc)
                orp[r * 3 + cc] = (float)R[r][cc];
    }
    if (tid >= 32 && tid < 42) {
        out[29184 + b * 10 + (tid - 32)] = (float)cv[144 + (tid - 32)];
    }
}

extern "C" void kernel_launch(void* const* d_in, const int* in_sizes, int n_in,
                              void* d_out, int out_size, void* d_ws, size_t ws_size,
                              hipStream_t stream) {
    const float* uv    = (const float*)d_in[0];
    const float* xm    = (const float*)d_in[1];
    const float* bs    = (const float*)d_in[2];
    const float* blend = (const float*)d_in[3];
    const float* Wp    = (const float*)d_in[4];
    const float* m00   = (const float*)d_in[5];
    const float* m11   = (const float*)d_in[6];
    const float* m02   = (const float*)d_in[7];
    const float* m12   = (const float*)d_in[8];
    const float* pbeta = (const float*)d_in[9];
    const float* vRp   = (const float*)d_in[10];
    float* out = (float*)d_out;
    double* Gpk = (double*)d_ws;
    float* pre = (float*)((char*)d_ws + G_BYTES);

    hipMemsetAsync(d_ws, 0, G_BYTES, stream);

    dim3 gP((Nn + 31) / 32, Bn);
    k_pre<<<gP, 1024, 0, stream>>>(uv, xm, bs, Wp, m00, m11, m02, m12, pre);

    dim3 gG(NBLK, Bn);
    k_gram<<<gG, 1024, 0, stream>>>(uv, xm, blend, Wp, m00, m11, m02, m12, pre, Gpk);

    k_solve<<<Bn, ST, 0, stream>>>(pbeta, vRp, Gpk, out);
}